// Round 4
// baseline (844.685 us; speedup 1.0000x reference)
//
#include <hip/hip_runtime.h>
#include <hip/hip_cooperative_groups.h>

namespace cg = cooperative_groups;

#define NN 12800
#define NE 204800
#define NBLK 256
#define NTHR 1024
#define NGRP ((NBLK * NTHR) / 16)            // 16384 16-lane groups
#define EPG  ((NE + NGRP - 1) / NGRP)        // 13 edges per group

// ---------------- static device scratch (~30 MB) ----------------
__device__ __align__(16) float g_out[NN * 16];   // current node features h
__device__ __align__(16) float g_aggr[NN * 16];  // message accumulator (atomics)
__device__ float g_invd[NN];                     // 1/max(indeg,1)
__device__ __align__(16) float g_A[NN * 272];    // per-node factor (17x16), row16 = bias
__device__ __align__(16) float g_ehs[NE * 16];   // edge hidden, src-sorted order
__device__ int g_scnt[NN];                       // src counts -> scan -> scatter cursor
__device__ int g_dcnt[NN];                       // dst in-degree
__device__ int g_sdst[NE];                       // dst per sorted edge
__device__ int g_ssrc[NE];                       // src per sorted edge

// ============================ fused cooperative path ========================
__global__ __launch_bounds__(NTHR, 4) void k_fused(
    const float* __restrict__ x, const int* __restrict__ ei,
    const float* __restrict__ attr,
    const float* __restrict__ lw, const float* __restrict__ lb,
    const float* __restrict__ w1, const float* __restrict__ b1,
    const float* __restrict__ nn2_w, const float* __restrict__ nn2_b,
    const float* __restrict__ cr, const float* __restrict__ cb,
    const float* __restrict__ wi, const float* __restrict__ wh,
    const float* __restrict__ bi, const float* __restrict__ bh,
    float* __restrict__ out_final)
{
    cg::grid_group grid = cg::this_grid();
    __shared__ float s_W2t[17 * 256];            // W2 transposed (+bias row 16)
    __shared__ float s_cr[256], s_wiT[768], s_whT[768];
    __shared__ float s_cb[16], s_bi[48], s_bh[48];

    const int t   = threadIdx.x;
    const int gid = blockIdx.x * NTHR + t;
    const int grp = gid >> 4;                    // global 16-lane group id
    const int k   = gid & 15;

    // ---- stage all weights to LDS once ----
    for (int i = t; i < 17 * 256; i += NTHR) {
        int j = i >> 8, r = i & 255;
        s_W2t[i] = (j < 16) ? nn2_w[r * 16 + j] : nn2_b[r];
    }
    if (t < 256) s_cr[t] = cr[t];
    if (t < 768) {
        int row = t >> 4, d = t & 15;
        s_wiT[d * 48 + row] = wi[t];
        s_whT[d * 48 + row] = wh[t];
    }
    if (t < 16) s_cb[t] = cb[t];
    if (t < 48) { s_bi[t] = bi[t]; s_bh[t] = bh[t]; }
    __syncthreads();

    // ---- P0: lin0 + zero aggr/counters (thread per node) ----
    if (gid < NN) {
        int n = gid;
        float x0 = x[n * 3 + 0], x1 = x[n * 3 + 1], x2 = x[n * 3 + 2];
        float v[16];
#pragma unroll
        for (int j = 0; j < 16; ++j) {
            float tt = lb[j] + x0 * lw[j * 3 + 0] + x1 * lw[j * 3 + 1] + x2 * lw[j * 3 + 2];
            v[j] = fmaxf(tt, 0.0f);
        }
#pragma unroll
        for (int j = 0; j < 16; j += 4) {
            *(float4*)(g_out + n * 16 + j)  = make_float4(v[j], v[j + 1], v[j + 2], v[j + 3]);
            *(float4*)(g_aggr + n * 16 + j) = make_float4(0.f, 0.f, 0.f, 0.f);
        }
        g_scnt[n] = 0;
        g_dcnt[n] = 0;
    }
    grid.sync();

    // ---- P1: count src / dst (thread per edge) ----
    if (gid < NE) {
        atomicAdd(&g_scnt[ei[gid]], 1);
        atomicAdd(&g_dcnt[ei[NE + gid]], 1);
    }
    grid.sync();

    // ---- P2: exclusive scan of scnt (single wave of block 0, shfl-based);
    //          invd for all nodes ----
    if (blockIdx.x == 0 && t < 64) {
        const int C = NN / 64;  // 200
        int tot = 0;
        for (int i = 0; i < C; ++i) tot += g_scnt[t * C + i];
        int incl = tot;
#pragma unroll
        for (int off = 1; off < 64; off <<= 1) {
            int v = __shfl_up(incl, off, 64);
            if (t >= off) incl += v;
        }
        int run = incl - tot;  // exclusive base for this lane's chunk
        for (int i = 0; i < C; ++i) {
            int v = g_scnt[t * C + i];
            g_scnt[t * C + i] = run;
            run += v;
        }
    }
    if (gid < NN) g_invd[gid] = 1.0f / fmaxf((float)g_dcnt[gid], 1.0f);
    grid.sync();

    // ---- P3: eh = relu(attr@W1.T+b1), scatter to src-sorted slot ----
    if (gid < NE) {
        int e = gid;
        int s = ei[e], d = ei[NE + e];
        float4 a = *(const float4*)(attr + e * 4);
        float v[16];
#pragma unroll
        for (int j = 0; j < 16; ++j) {
            float tt = b1[j] + a.x * w1[j * 4 + 0] + a.y * w1[j * 4 + 1] +
                       a.z * w1[j * 4 + 2] + a.w * w1[j * 4 + 3];
            v[j] = fmaxf(tt, 0.0f);
        }
        int pos = atomicAdd(&g_scnt[s], 1);
        g_sdst[pos] = d;
        g_ssrc[pos] = s;
#pragma unroll
        for (int j = 0; j < 16; j += 4)
            *(float4*)(g_ehs + pos * 16 + j) = make_float4(v[j], v[j + 1], v[j + 2], v[j + 3]);
    }
    // ---- P4 (same phase): initial A from g_out ----
    if (grp < NN) {
        int n = grp;
        float o[16];
#pragma unroll
        for (int d = 0; d < 16; d += 4) {
            float4 v = *(const float4*)(g_out + n * 16 + d);
            o[d] = v.x; o[d + 1] = v.y; o[d + 2] = v.z; o[d + 3] = v.w;
        }
        float* Arow = g_A + n * 272;
#pragma unroll
        for (int j = 0; j < 17; ++j) {
            float acc = 0.0f;
#pragma unroll
            for (int d = 0; d < 16; ++d) acc += o[d] * s_W2t[j * 256 + d * 16 + k];
            Arow[j * 16 + k] = acc;
        }
    }
    grid.sync();

    // ---- 6 rounds ----
    for (int r = 0; r < 6; ++r) {
        // edge phase: contiguous chunk of src-sorted edges per group
        int e0 = grp * EPG;
        int e1 = e0 + EPG; if (e1 > NE) e1 = NE;
        for (int p = e0; p < e1; ++p) {
            int s = g_ssrc[p];
            int d = g_sdst[p];
            float h[16];
#pragma unroll
            for (int j = 0; j < 16; j += 4) {
                float4 v = *(const float4*)(g_ehs + p * 16 + j);
                h[j] = v.x; h[j + 1] = v.y; h[j + 2] = v.z; h[j + 3] = v.w;
            }
            const float* Ar = g_A + s * 272 + k;
            float acc = Ar[256];  // bias row
#pragma unroll
            for (int j = 0; j < 16; ++j) acc += h[j] * Ar[j * 16];
            atomicAdd(&g_aggr[d * 16 + k], acc);
        }
        grid.sync();

        // node phase: group per node, 16-wide shfl (no block barrier)
        if (grp < NN) {
            int n = grp;
            float o[16];
#pragma unroll
            for (int d = 0; d < 16; d += 4) {
                float4 v = *(const float4*)(g_out + n * 16 + d);
                o[d] = v.x; o[d + 1] = v.y; o[d + 2] = v.z; o[d + 3] = v.w;
            }
            float ag = g_aggr[n * 16 + k];
            g_aggr[n * 16 + k] = 0.0f;          // re-zero for next round
            float idg = g_invd[n];

            float acc = s_cb[k] + ag * idg;
#pragma unroll
            for (int d = 0; d < 16; ++d) acc += o[d] * s_cr[d * 16 + k];
            float m = fmaxf(acc, 0.0f);

            float ir = s_bi[k], iz = s_bi[16 + k], in_ = s_bi[32 + k];
            float hr = s_bh[k], hz = s_bh[16 + k], hh = s_bh[32 + k];
#pragma unroll
            for (int d = 0; d < 16; ++d) {
                float md = __shfl(m, d, 16);
                ir  += md * s_wiT[d * 48 + k];
                iz  += md * s_wiT[d * 48 + 16 + k];
                in_ += md * s_wiT[d * 48 + 32 + k];
                hr  += o[d] * s_whT[d * 48 + k];
                hz  += o[d] * s_whT[d * 48 + 16 + k];
                hh  += o[d] * s_whT[d * 48 + 32 + k];
            }
            float rg = 1.0f / (1.0f + __expf(-(ir + hr)));
            float z  = 1.0f / (1.0f + __expf(-(iz + hz)));
            float nh = tanhf(in_ + rg * hh);
            float hnew = (1.0f - z) * nh + z * o[k];

            if (r == 5) {
                out_final[n * 16 + k] = hnew;
            } else {
                g_out[n * 16 + k] = hnew;
                float* Arow = g_A + n * 272;
#pragma unroll
                for (int j = 0; j < 17; ++j) {
                    float a2 = 0.0f;
#pragma unroll
                    for (int d = 0; d < 16; ++d) {
                        float hd = __shfl(hnew, d, 16);
                        a2 += hd * s_W2t[j * 256 + d * 16 + k];
                    }
                    Arow[j * 16 + k] = a2;
                }
            }
        }
        grid.sync();
    }
}

// ======================= fallback multi-kernel path (verified R2) ===========
__global__ __launch_bounds__(256) void k_setup(const float* __restrict__ x,
                                               const float* __restrict__ lw,
                                               const float* __restrict__ lb) {
    int n = blockIdx.x * 256 + threadIdx.x;
    float x0 = x[n * 3 + 0], x1 = x[n * 3 + 1], x2 = x[n * 3 + 2];
    float v[16];
#pragma unroll
    for (int j = 0; j < 16; ++j) {
        float t = lb[j] + x0 * lw[j * 3 + 0] + x1 * lw[j * 3 + 1] + x2 * lw[j * 3 + 2];
        v[j] = fmaxf(t, 0.0f);
    }
#pragma unroll
    for (int j = 0; j < 16; j += 4) {
        *(float4*)(g_out + n * 16 + j)  = make_float4(v[j], v[j + 1], v[j + 2], v[j + 3]);
        *(float4*)(g_aggr + n * 16 + j) = make_float4(0.f, 0.f, 0.f, 0.f);
    }
    g_scnt[n] = 0;
    g_dcnt[n] = 0;
}

__global__ __launch_bounds__(256) void k_count(const int* __restrict__ ei) {
    int e = blockIdx.x * 256 + threadIdx.x;
    atomicAdd(&g_scnt[ei[e]], 1);
    atomicAdd(&g_dcnt[ei[NE + e]], 1);
}

__global__ __launch_bounds__(256) void k_scan() {
    __shared__ int part[256];
    const int C = NN / 256;
    int t = threadIdx.x;
    int sum = 0;
    for (int i = 0; i < C; ++i) sum += g_scnt[t * C + i];
    part[t] = sum;
    __syncthreads();
    for (int off = 1; off < 256; off <<= 1) {
        int v = (t >= off) ? part[t - off] : 0;
        __syncthreads();
        part[t] += v;
        __syncthreads();
    }
    int run = (t > 0) ? part[t - 1] : 0;
    for (int i = 0; i < C; ++i) {
        int v = g_scnt[t * C + i];
        g_scnt[t * C + i] = run;
        run += v;
    }
    for (int i = t; i < NN; i += 256)
        g_invd[i] = 1.0f / fmaxf((float)g_dcnt[i], 1.0f);
}

__global__ __launch_bounds__(256) void k_scatter(const int* __restrict__ ei,
                                                 const float* __restrict__ attr,
                                                 const float* __restrict__ w1,
                                                 const float* __restrict__ b1) {
    int e = blockIdx.x * 256 + threadIdx.x;
    int s = ei[e], d = ei[NE + e];
    float4 a = *(const float4*)(attr + e * 4);
    float v[16];
#pragma unroll
    for (int j = 0; j < 16; ++j) {
        float t = b1[j] + a.x * w1[j * 4 + 0] + a.y * w1[j * 4 + 1] +
                  a.z * w1[j * 4 + 2] + a.w * w1[j * 4 + 3];
        v[j] = fmaxf(t, 0.0f);
    }
    int pos = atomicAdd(&g_scnt[s], 1);
    g_sdst[pos] = d;
    g_ssrc[pos] = s;
#pragma unroll
    for (int j = 0; j < 16; j += 4)
        *(float4*)(g_ehs + pos * 16 + j) = make_float4(v[j], v[j + 1], v[j + 2], v[j + 3]);
}

__global__ __launch_bounds__(256) void k_expand(const float* __restrict__ nn2_w,
                                                const float* __restrict__ nn2_b) {
    __shared__ float W2t[17 * 256];
    int tid = threadIdx.x;
    for (int m = tid; m < 17 * 256; m += 256) {
        int j = m >> 8, r = m & 255;
        W2t[m] = (j < 16) ? nn2_w[r * 16 + j] : nn2_b[r];
    }
    __syncthreads();
    int grp = tid >> 4, k = tid & 15;
    int n = blockIdx.x * 16 + grp;
    float o[16];
#pragma unroll
    for (int d = 0; d < 16; d += 4) {
        float4 v = *(const float4*)(g_out + n * 16 + d);
        o[d] = v.x; o[d + 1] = v.y; o[d + 2] = v.z; o[d + 3] = v.w;
    }
    float* Arow = g_A + n * 272;
#pragma unroll
    for (int j = 0; j < 17; ++j) {
        float acc = 0.0f;
#pragma unroll
        for (int d = 0; d < 16; ++d) acc += o[d] * W2t[j * 256 + d * 16 + k];
        Arow[j * 16 + k] = acc;
    }
}

__global__ __launch_bounds__(256) void k_edge() {
    int tid = threadIdx.x;
    int grp = tid >> 4, k = tid & 15;
    int p = blockIdx.x * 16 + grp;
    int s = g_ssrc[p];
    int d = g_sdst[p];
    float h[16];
#pragma unroll
    for (int j = 0; j < 16; j += 4) {
        float4 v = *(const float4*)(g_ehs + p * 16 + j);
        h[j] = v.x; h[j + 1] = v.y; h[j + 2] = v.z; h[j + 3] = v.w;
    }
    const float* Ar = g_A + s * 272 + k;
    float acc = Ar[256];
#pragma unroll
    for (int j = 0; j < 16; ++j) acc += h[j] * Ar[j * 16];
    atomicAdd(&g_aggr[d * 16 + k], acc);
}

__global__ __launch_bounds__(256) void k_nodeA(const float* __restrict__ cr,
                                               const float* __restrict__ cb,
                                               const float* __restrict__ wi,
                                               const float* __restrict__ wh,
                                               const float* __restrict__ bi,
                                               const float* __restrict__ bh,
                                               const float* __restrict__ nn2_w,
                                               const float* __restrict__ nn2_b,
                                               float* __restrict__ out_final,
                                               int last) {
    __shared__ float s_cr[256], s_wiT[768], s_whT[768], s_W2t[17 * 256];
    __shared__ float s_cb[16], s_bi[48], s_bh[48], s_m[256];
    int t = threadIdx.x;
    s_cr[t] = cr[t];
    for (int i = t; i < 768; i += 256) {
        int row = i >> 4, d = i & 15;
        s_wiT[d * 48 + row] = wi[i];
        s_whT[d * 48 + row] = wh[i];
    }
    for (int i = t; i < 17 * 256; i += 256) {
        int j = i >> 8, r = i & 255;
        s_W2t[i] = (j < 16) ? nn2_w[r * 16 + j] : nn2_b[r];
    }
    if (t < 16) s_cb[t] = cb[t];
    if (t < 48) { s_bi[t] = bi[t]; s_bh[t] = bh[t]; }
    __syncthreads();

    int grp = t >> 4, k = t & 15;
    int n = blockIdx.x * 16 + grp;
    float o[16];
#pragma unroll
    for (int d = 0; d < 16; d += 4) {
        float4 v = *(const float4*)(g_out + n * 16 + d);
        o[d] = v.x; o[d + 1] = v.y; o[d + 2] = v.z; o[d + 3] = v.w;
    }
    float ag = g_aggr[n * 16 + k];
    g_aggr[n * 16 + k] = 0.0f;
    float idg = g_invd[n];

    float acc = s_cb[k] + ag * idg;
#pragma unroll
    for (int d = 0; d < 16; ++d) acc += o[d] * s_cr[d * 16 + k];
    float m = fmaxf(acc, 0.0f);
    s_m[grp * 16 + k] = m;
    __syncthreads();

    float md[16];
#pragma unroll
    for (int d = 0; d < 16; ++d) md[d] = s_m[grp * 16 + d];
    float ir = s_bi[k], iz = s_bi[16 + k], in_ = s_bi[32 + k];
    float hr = s_bh[k], hz = s_bh[16 + k], hh = s_bh[32 + k];
#pragma unroll
    for (int d = 0; d < 16; ++d) {
        ir  += md[d] * s_wiT[d * 48 + k];
        iz  += md[d] * s_wiT[d * 48 + 16 + k];
        in_ += md[d] * s_wiT[d * 48 + 32 + k];
        hr  += o[d] * s_whT[d * 48 + k];
        hz  += o[d] * s_whT[d * 48 + 16 + k];
        hh  += o[d] * s_whT[d * 48 + 32 + k];
    }
    float r = 1.0f / (1.0f + __expf(-(ir + hr)));
    float z = 1.0f / (1.0f + __expf(-(iz + hz)));
    float nh = tanhf(in_ + r * hh);
    float hnew = (1.0f - z) * nh + z * o[k];

    if (last) {
        out_final[n * 16 + k] = hnew;
    } else {
        g_out[n * 16 + k] = hnew;
        __syncthreads();
        s_m[grp * 16 + k] = hnew;
        __syncthreads();
        float on[16];
#pragma unroll
        for (int d = 0; d < 16; ++d) on[d] = s_m[grp * 16 + d];
        float* Arow = g_A + n * 272;
#pragma unroll
        for (int j = 0; j < 17; ++j) {
            float a2 = 0.0f;
#pragma unroll
            for (int d = 0; d < 16; ++d) a2 += on[d] * s_W2t[j * 256 + d * 16 + k];
            Arow[j * 16 + k] = a2;
        }
    }
}

extern "C" void kernel_launch(void* const* d_in, const int* in_sizes, int n_in,
                              void* d_out, int out_size, void* d_ws, size_t ws_size,
                              hipStream_t stream) {
    const float* x         = (const float*)d_in[0];
    const int*   ei        = (const int*)d_in[1];
    const float* edge_attr = (const float*)d_in[2];
    const float* lin0_w    = (const float*)d_in[3];
    const float* lin0_b    = (const float*)d_in[4];
    const float* nn1_w     = (const float*)d_in[5];
    const float* nn1_b     = (const float*)d_in[6];
    const float* nn2_w     = (const float*)d_in[7];
    const float* nn2_b     = (const float*)d_in[8];
    const float* conv_root = (const float*)d_in[9];
    const float* conv_bias = (const float*)d_in[10];
    const float* gru_w_ih  = (const float*)d_in[11];
    const float* gru_w_hh  = (const float*)d_in[12];
    const float* gru_b_ih  = (const float*)d_in[13];
    const float* gru_b_hh  = (const float*)d_in[14];
    float* out = (float*)d_out;

    void* args[] = {
        (void*)&x, (void*)&ei, (void*)&edge_attr,
        (void*)&lin0_w, (void*)&lin0_b,
        (void*)&nn1_w, (void*)&nn1_b,
        (void*)&nn2_w, (void*)&nn2_b,
        (void*)&conv_root, (void*)&conv_bias,
        (void*)&gru_w_ih, (void*)&gru_w_hh,
        (void*)&gru_b_ih, (void*)&gru_b_hh,
        (void*)&out,
    };
    hipError_t err = hipLaunchCooperativeKernel((const void*)k_fused, dim3(NBLK),
                                                dim3(NTHR), args, 0, stream);
    if (err != hipSuccess) {
        // fallback: verified multi-kernel path (identical math)
        k_setup<<<NN / 256, 256, 0, stream>>>(x, lin0_w, lin0_b);
        k_count<<<NE / 256, 256, 0, stream>>>(ei);
        k_scan<<<1, 256, 0, stream>>>();
        k_scatter<<<NE / 256, 256, 0, stream>>>(ei, edge_attr, nn1_w, nn1_b);
        k_expand<<<NN / 16, 256, 0, stream>>>(nn2_w, nn2_b);
        for (int r = 0; r < 6; ++r) {
            k_edge<<<NE / 16, 256, 0, stream>>>();
            k_nodeA<<<NN / 16, 256, 0, stream>>>(conv_root, conv_bias, gru_w_ih,
                                                 gru_w_hh, gru_b_ih, gru_b_hh,
                                                 nn2_w, nn2_b, out, r == 5 ? 1 : 0);
        }
    }
}